// Round 13
// baseline (713.480 us; speedup 1.0000x reference)
//
#include <hip/hip_runtime.h>

// 8-layer transformer LM forward. V=128, E=512, L=8, H=8, B=4, T=1024.
// Round 20: (a) QKV GEMM BM=256 (grid 384, 2 blocks/CU, 80KB LDS): W L3
// re-read 32x -> 16x, reads/MFMA 0.75 -> 0.5, and each wave owns exactly one
// 64-token kt tile so vtile sums reduce with 2 shfls (no LDS/barrier).
// (b) pre-LN stream y_f -> bf16 (z_b): aff2/ffn2 write bf16, ln reads bf16
// (~128 MB/forward saved; absmax headroom spend like R19's residual move).
// Everything else frozen at R19 (711 us): bf16 residual, KVBLK=128 attn,
// M x K split gemm64, BM=32 head+loss.

#define V_  128
#define E_  512
#define L_  8
#define H_  8
#define B_  4
#define T_  1024
#define N_  (B_*T_)    // 4096 tokens
#define DH_ 64
#define E3_ 1536

typedef __attribute__((ext_vector_type(8))) short   bf16x8;   // MFMA A/B frag
typedef __attribute__((ext_vector_type(4))) float   floatx4;  // MFMA C/D frag

// swizzled LDS offset (ushort units): 64-wide rows, 8-elem chunks XORed by row&7
#define SW(row,k8) (((row) << 6) + ((((k8) ^ ((row) & 7))) << 3))
// 128-wide rows (16 chunks), chunk XORed by row&7 within low 3 bits
#define SW128(row,c) (((row) << 7) + ((((c) ^ ((row) & 7))) << 3))

__device__ __forceinline__ unsigned short f2bf(float f) {
    union { float f; unsigned int i; } v; v.f = f;
    unsigned int x = v.i;
    return (unsigned short)((x + 0x7fffu + ((x >> 16) & 1u)) >> 16);  // RNE
}
__device__ __forceinline__ float bf2f(unsigned short u) {
    union { unsigned int i; float f; } v; v.i = ((unsigned int)u) << 16; return v.f;
}
__device__ __forceinline__ void gload_lds16(const void* g, void* l) {
    __builtin_amdgcn_global_load_lds(
        (const __attribute__((address_space(1))) unsigned int*)g,
        (__attribute__((address_space(3))) unsigned int*)l, 16, 0, 0);
}

// XCD-grouped remap: grid (nx, ny), ny%8==0.
__device__ __forceinline__ void xcd_remap(int& mstrip, int& nblk) {
    int nx = gridDim.x;
    int flat = blockIdx.y * nx + blockIdx.x;
    int xcd = flat & 7;
    int j = flat >> 3;
    int per_xcd = gridDim.y >> 3;
    mstrip = xcd * per_xcd + j / nx;
    nblk = j % nx;
}

// ---------------- single-dispatch fp32 -> bf16 weight convert (8-wide) -------
#define CVT_N0 6291456
#define CVT_N1 2097152
#define CVT_TOT (CVT_N0 + 4*CVT_N1 + V_*E_)
__global__ void cvt_all_kernel(const float* __restrict__ s0, const float* __restrict__ s1,
                               const float* __restrict__ s2, const float* __restrict__ s3,
                               const float* __restrict__ s4, const float* __restrict__ s5,
                               unsigned short* __restrict__ dst) {
    long i = (long)(blockIdx.x * blockDim.x + threadIdx.x) * 8;
    if (i >= CVT_TOT) return;
    const float* src; long off;
    if      (i < CVT_N0)               { src = s0; off = i; }
    else if (i < CVT_N0 + CVT_N1)      { src = s1; off = i - CVT_N0; }
    else if (i < CVT_N0 + 2*CVT_N1)    { src = s2; off = i - CVT_N0 - CVT_N1; }
    else if (i < CVT_N0 + 3*CVT_N1)    { src = s3; off = i - CVT_N0 - 2L*CVT_N1; }
    else if (i < CVT_N0 + 4*CVT_N1)    { src = s4; off = i - CVT_N0 - 3L*CVT_N1; }
    else                               { src = s5; off = i - CVT_N0 - 4L*CVT_N1; }
    float4 v0 = *(const float4*)(src + off);
    float4 v1 = *(const float4*)(src + off + 4);
    ushort4 o0, o1;
    o0.x = f2bf(v0.x); o0.y = f2bf(v0.y); o0.z = f2bf(v0.z); o0.w = f2bf(v0.w);
    o1.x = f2bf(v1.x); o1.y = f2bf(v1.y); o1.z = f2bf(v1.z); o1.w = f2bf(v1.w);
    *(ushort4*)(dst + i)     = o0;
    *(ushort4*)(dst + i + 4) = o1;
}

// ---------------- embedding: write bf16 only ----------------
__global__ void embed_kernel(const int* __restrict__ tok, const float* __restrict__ emb,
                             unsigned short* __restrict__ xb) {
    int idx = blockIdx.x * blockDim.x + threadIdx.x;
    if (idx >= N_ * E_) return;
    int n = idx >> 9;
    int e = idx & (E_ - 1);
    xb[idx] = f2bf(emb[tok[n] * E_ + e]);
}

// ---------------- MFMA GEMM: BM=64, BN=64, paired-K, M x K wave split --------
// ADDRES reads the bf16 residual copy (resB); output bf16 only (Cb).
template<int RELU, int ADDRES>
__global__ __launch_bounds__(256) void gemm64(
    const unsigned short* __restrict__ A, const unsigned short* __restrict__ W,
    const float* __restrict__ bias, const unsigned short* __restrict__ resB,
    unsigned short* __restrict__ Cb,
    int M, int Nout, int K)
{
    __shared__ unsigned short Asm[4][64 * 64];
    __shared__ unsigned short Bsm[4][64 * 64];
    int tid = threadIdx.x;
    int wv = tid >> 6, ln = tid & 63;
    int lquad = ln >> 4, lmod = ln & 15;
    int mh = wv & 1, kh = wv >> 1;
    int mstrip, nblk;
    xcd_remap(mstrip, nblk);
    int m0 = mstrip * 64, n0 = nblk * 64;

    floatx4 acc[2][4] = {};

    auto stage = [&](int k0, int s) {
        #pragma unroll
        for (int c = 0; c < 2; ++c) {
            int cc = tid + 256 * c;
            int r = cc >> 3, k8s = (cc & 7) ^ (r & 7);
            gload_lds16(A + (size_t)(m0 + r) * K + k0 + 8 * k8s,
                        &Asm[s][2048 * c + 512 * wv]);
        }
        #pragma unroll
        for (int c = 0; c < 2; ++c) {
            int cc = tid + 256 * c;
            int r = cc >> 3, k8s = (cc & 7) ^ (r & 7);
            gload_lds16(W + (size_t)(n0 + r) * K + k0 + 8 * k8s,
                        &Bsm[s][2048 * c + 512 * wv]);
        }
    };

    int np = K >> 7;
    stage(0, 0);
    stage(64, 1);
    __syncthreads();

    for (int t = 0; t < np; ++t) {
        if (t + 1 < np) {
            stage((2 * t + 2) << 6, (2 * t + 2) & 3);
            stage((2 * t + 3) << 6, (2 * t + 3) & 3);
        }
        #pragma unroll
        for (int half = 0; half < 2; ++half) {
            int s = (2 * t + half) & 3;
            bf16x8 af[2], bfr[4];
            #pragma unroll
            for (int i = 0; i < 2; ++i)
                af[i] = *(const bf16x8*)&Asm[s][SW(32 * mh + 16 * i + lmod, 4 * kh + lquad)];
            #pragma unroll
            for (int j = 0; j < 4; ++j)
                bfr[j] = *(const bf16x8*)&Bsm[s][SW(16 * j + lmod, 4 * kh + lquad)];
            #pragma unroll
            for (int i = 0; i < 2; ++i)
                #pragma unroll
                for (int j = 0; j < 4; ++j)
                    acc[i][j] = __builtin_amdgcn_mfma_f32_16x16x32_bf16(af[i], bfr[j], acc[i][j], 0, 0, 0);
        }
        if (t + 1 < np) __syncthreads();
    }

    float* redF = (float*)&Asm[0][0];
    if (kh == 1) {
        #pragma unroll
        for (int i = 0; i < 2; ++i)
            #pragma unroll
            for (int j = 0; j < 4; ++j) {
                int bidx = i * 4 + j;
                *(floatx4*)&redF[mh * 2048 + ln * 32 + (((bidx ^ (ln & 7))) << 2)] = acc[i][j];
            }
    }
    __syncthreads();
    if (kh == 0) {
        #pragma unroll
        for (int i = 0; i < 2; ++i)
            #pragma unroll
            for (int j = 0; j < 4; ++j) {
                int bidx = i * 4 + j;
                floatx4 part = *(const floatx4*)&redF[mh * 2048 + ln * 32 + (((bidx ^ (ln & 7))) << 2)];
                int n = n0 + 16 * j + lmod;
                float bj = bias[n];
                #pragma unroll
                for (int v = 0; v < 4; ++v) {
                    int m = m0 + 32 * mh + 16 * i + 4 * lquad + v;
                    float val = acc[i][j][v] + part[v] + bj;
                    if (ADDRES) val += bf2f(resB[(size_t)m * Nout + n]);
                    if (RELU) val = fmaxf(val, 0.f);
                    Cb[(size_t)m * Nout + n] = f2bf(val);
                }
            }
    }
}

// ---------------- QKV GEMM, BM=256, fused V-transpose, XCD-grouped -----------
// Grid (24, 16) = 384 blocks, 80 KB LDS = 2 blocks/CU. Wave wv owns rows
// 64wv..64wv+63 (= one kt tile for V blocks -> vtile via 2 shfls, no LDS).
__global__ __launch_bounds__(256) void gemm_qkv(
    const unsigned short* __restrict__ A, const unsigned short* __restrict__ W,
    const float* __restrict__ bias, unsigned short* __restrict__ Cb,
    unsigned short* __restrict__ vt_g, float* __restrict__ vtile, int K)
{
    __shared__ unsigned short Asm[2][256 * 64];   // 2 x 32 KB
    __shared__ unsigned short Bsm[2][64 * 64];    // 2 x  8 KB
    int tid = threadIdx.x;
    int wv = tid >> 6, ln = tid & 63;
    int lquad = ln >> 4, lmod = ln & 15;
    int mstrip, nblk;
    xcd_remap(mstrip, nblk);
    int m0 = mstrip * 256, n0 = nblk * 64;

    floatx4 acc[4][4] = {};

    auto stage = [&](int k0, int pb) {
        #pragma unroll
        for (int c = 0; c < 8; ++c) {               // A: 2048 chunks, 8/thread
            int cc = tid + 256 * c;
            int r = cc >> 3, k8s = (cc & 7) ^ (r & 7);
            gload_lds16(A + (size_t)(m0 + r) * K + k0 + 8 * k8s,
                        &Asm[pb][2048 * c + 512 * wv]);
        }
        #pragma unroll
        for (int c = 0; c < 2; ++c) {               // B: 512 chunks, 2/thread
            int cc = tid + 256 * c;
            int r = cc >> 3, k8s = (cc & 7) ^ (r & 7);
            gload_lds16(W + (size_t)(n0 + r) * K + k0 + 8 * k8s,
                        &Bsm[pb][2048 * c + 512 * wv]);
        }
    };

    int nt = K >> 6;
    stage(0, 0);
    __syncthreads();
    for (int t = 0; t < nt; ++t) {
        int pb = t & 1;
        if (t + 1 < nt) stage((t + 1) << 6, pb ^ 1);
        #pragma unroll
        for (int ks = 0; ks < 2; ++ks) {
            bf16x8 af[4], bfr[4];
            #pragma unroll
            for (int i = 0; i < 4; ++i)
                af[i] = *(const bf16x8*)&Asm[pb][SW(64 * wv + 16 * i + lmod, ks * 4 + lquad)];
            #pragma unroll
            for (int j = 0; j < 4; ++j)
                bfr[j] = *(const bf16x8*)&Bsm[pb][SW(16 * j + lmod, ks * 4 + lquad)];
            #pragma unroll
            for (int i = 0; i < 4; ++i)
                #pragma unroll
                for (int j = 0; j < 4; ++j)
                    acc[i][j] = __builtin_amdgcn_mfma_f32_16x16x32_bf16(af[i], bfr[j], acc[i][j], 0, 0, 0);
        }
        if (t + 1 < nt) __syncthreads();
    }

    if ((n0 % 192) != 128) {
        // Q/K columns: standard bf16 write
        #pragma unroll
        for (int i = 0; i < 4; ++i)
            #pragma unroll
            for (int j = 0; j < 4; ++j) {
                int n = n0 + 16 * j + lmod;
                float bj = bias[n];
                #pragma unroll
                for (int v = 0; v < 4; ++v) {
                    int m = m0 + 64 * wv + 16 * i + 4 * lquad + v;
                    Cb[(size_t)m * E3_ + n] = f2bf(acc[i][j][v] + bj);
                }
            }
    } else {
        // pure-V block: transposed vt_g + per-wave kt tile sums (no LDS)
        int h = n0 / 192;
        int b = m0 >> 10;
        int bh = b * 8 + h;
        int t0 = m0 & 1023;
        int kt = (t0 >> 6) + wv;                   // wave wv owns one kt tile
        float sj[4] = {0.f, 0.f, 0.f, 0.f};
        #pragma unroll
        for (int j = 0; j < 4; ++j) {
            float bj = bias[n0 + 16 * j + lmod];
            #pragma unroll
            for (int i = 0; i < 4; ++i) {
                union { unsigned short u[4]; uint2 q; } pk;
                #pragma unroll
                for (int v = 0; v < 4; ++v) {
                    unsigned short r = f2bf(acc[i][j][v] + bj);
                    pk.u[v] = r;
                    sj[j] += bf2f(r);
                }
                int t = t0 + 64 * wv + 16 * i + 4 * lquad;
                *(uint2*)&vt_g[((size_t)(bh * 64 + 16 * j + lmod)) * T_ + t] = pk.q;
            }
        }
        #pragma unroll
        for (int j = 0; j < 4; ++j) {
            sj[j] += __shfl_xor(sj[j], 16);
            sj[j] += __shfl_xor(sj[j], 32);
        }
        if (lquad == 0)
            #pragma unroll
            for (int j = 0; j < 4; ++j)
                vtile[((size_t)bh * 16 + kt) * 64 + 16 * j + lmod] = sj[j];
    }
}

// ---------------- MFMA flash attention, KVBLK=128, mask-specialized ----------
__global__ __launch_bounds__(256) void attn_mfma(const unsigned short* __restrict__ qkv,
                                                 const unsigned short* __restrict__ vt_g,
                                                 const float* __restrict__ vtile,
                                                 unsigned short* __restrict__ outb)
{
    __shared__ unsigned short Qs[64 * 64];         // [q][d]   8 KB
    __shared__ unsigned short Ks[2][128 * 64];     // [k][d]  32 KB, dbuf
    __shared__ unsigned short Vs[64 * 128];        // [d][k]  16 KB, single
    __shared__ unsigned short Ps[64 * 128];        // [q][k]  16 KB, wave-private rows

    int tid = threadIdx.x;
    int wv = tid >> 6, ln = tid & 63;
    int lquad = ln >> 4, lmod = ln & 15;
    int bh = blockIdx.x;
    int y = blockIdx.y;
    int qt = (y < 8) ? y : 23 - y;                 // complementary pairing
    int b = bh >> 3, h = bh & 7;
    int q0 = qt * 64;
    int nt = (qt >> 1) + 1;                        // 128-wide k-tiles
    const float scale = 0.125f;
    size_t base = (size_t)b * T_ * E3_ + h * 192;

    auto stageK = [&](int k0, int pb) {
        #pragma unroll
        for (int c = 0; c < 4; ++c) {
            int cc = tid + 256 * c;
            int r = cc >> 3, k8s = (cc & 7) ^ (r & 7);
            gload_lds16(qkv + base + (size_t)(k0 + r) * E3_ + 64 + 8 * k8s,
                        &Ks[pb][2048 * c + 512 * wv]);
        }
    };
    auto stageV = [&](int k0) {
        #pragma unroll
        for (int c = 0; c < 4; ++c) {
            int cc = tid + 256 * c;
            int r = cc >> 4, c16 = cc & 15;
            int k8s = c16 ^ (r & 7);
            gload_lds16(vt_g + ((size_t)(bh * 64 + r)) * T_ + k0 + 8 * k8s,
                        &Vs[2048 * c + 512 * wv]);
        }
    };

    // prologue: Q + K tile 0
    #pragma unroll
    for (int c = 0; c < 2; ++c) {
        int cc = tid + 256 * c;
        int r = cc >> 3, k8s = (cc & 7) ^ (r & 7);
        gload_lds16(qkv + base + (size_t)(q0 + r) * E3_ + 8 * k8s, Qs + 2048 * c + 512 * wv);
    }
    stageK(0, 0);
    __syncthreads();

    // hoisted Q fragments (loop-invariant)
    bf16x8 aq[2];
    #pragma unroll
    for (int ks = 0; ks < 2; ++ks)
        aq[ks] = *(const bf16x8*)&Qs[SW(16 * wv + lmod, ks * 4 + lquad)];

    float lrow[4] = {0.f, 0.f, 0.f, 0.f};
    floatx4 Oa[4] = {};

    for (int t = 0; t < nt; ++t) {
        int pb = t & 1;
        int k0 = t * 128;
        stageV(k0);                                 // lands under QK + softmax
        if (t + 1 < nt) stageK(k0 + 128, pb ^ 1);   // prefetch next K

        // S strip = Q[16 rows] . K^T (128 cols)
        floatx4 sacc[8] = {};
        #pragma unroll
        for (int ks = 0; ks < 2; ++ks)
            #pragma unroll
            for (int j = 0; j < 8; ++j) {
                bf16x8 bk = *(const bf16x8*)&Ks[pb][SW(16 * j + lmod, ks * 4 + lquad)];
                sacc[j] = __builtin_amdgcn_mfma_f32_16x16x32_bf16(aq[ks], bk, sacc[j], 0, 0, 0);
            }

        // softmax: p = exp(s*scale); only the last tile has masked elements.
        if (t + 1 < nt) {
            #pragma unroll
            for (int v = 0; v < 4; ++v) {
                int row = 16 * wv + 4 * lquad + v;
                #pragma unroll
                for (int j = 0; j < 8; ++j) {
                    float p = __expf(sacc[j][v] * scale);
                    lrow[v] += p;
                    int col = 16 * j + lmod;
                    Ps[SW128(row, col >> 3) + (col & 7)] = f2bf(p);
                }
            }
        } else {
            #pragma unroll
            for (int v = 0; v < 4; ++v) {
                int qg = q0 + 16 * wv + 4 * lquad + v;
                int row = 16 * wv + 4 * lquad + v;
                #pragma unroll
                for (int j = 0; j < 8; ++j) {
                    int kg = k0 + 16 * j + lmod;
                    float p = (kg <= qg) ? __expf(sacc[j][v] * scale) : 1.0f;
                    lrow[v] += p;
                    int col = 16 * j + lmod;
                    Ps[SW128(row, col >> 3) + (col & 7)] = f2bf(p);
                }
            }
        }

        // V ready for ALL waves + own Ps drained; K prefetch stays in flight
        if (t + 1 < nt) asm volatile("s_waitcnt vmcnt(4) lgkmcnt(0)" ::: "memory");
        else            asm volatile("s_waitcnt vmcnt(0) lgkmcnt(0)" ::: "memory");
        __builtin_amdgcn_s_barrier();
        __builtin_amdgcn_sched_barrier(0);

        // O += P . V  (K=128 -> 4 ks-steps)
        #pragma unroll
        for (int ks2 = 0; ks2 < 4; ++ks2) {
            bf16x8 ap = *(const bf16x8*)&Ps[SW128(16 * wv + lmod, 4 * ks2 + lquad)];
            #pragma unroll
            for (int f = 0; f < 4; ++f) {
                bf16x8 bv = *(const bf16x8*)&Vs[SW128(16 * f + lmod, 4 * ks2 + lquad)];
                Oa[f] = __builtin_amdgcn_mfma_f32_16x16x32_bf16(ap, bv, Oa[f], 0, 0, 0);
            }
        }
        if (t + 1 < nt) __syncthreads();   // K landed + WAR on Vs/Ps/Ks
    }

    #pragma unroll
    for (int v = 0; v < 4; ++v)
        #pragma unroll
        for (int msk = 1; msk < 16; msk <<= 1) lrow[v] += __shfl_xor(lrow[v], msk);

    int s0 = 2 * nt;
    if (s0 < 16) {
        float Km = (float)((16 - s0) * 64);
        #pragma unroll
        for (int v = 0; v < 4; ++v) lrow[v] += Km;
        #pragma unroll
        for (int f = 0; f < 4; ++f) {
            float sv = 0.f;
            for (int kt = s0; kt < 16; ++kt)
                sv += vtile[((size_t)bh * 16 + kt) * 64 + 16 * f + lmod];
            #pragma unroll
            for (int v = 0; v < 4; ++v) Oa[f][v] += sv;
        }
    }

    #pragma unroll
    for (int f = 0; f < 4; ++f)
        #pragma unroll
        for (int v = 0; v < 4; ++v) {
            int q = q0 + 16 * wv + 4 * lquad + v;
            outb[(size_t)(b * T_ + q) * E_ + h * DH_ + 16 * f + lmod] = f2bf(Oa[f][v] / lrow[v]);
        }
}

// ---------------- LN: bf16 in (pre-LN z), bf16 out ---------------------------
__global__ __launch_bounds__(256) void ln_kernel(
    const unsigned short* __restrict__ z,
    const float* __restrict__ s, const float* __restrict__ bpar,
    unsigned short* __restrict__ outB)
{
    int tid = threadIdx.x, wv = tid >> 6, ln = tid & 63;
    int n = blockIdx.x * 4 + wv;
    int e = ln * 8;
    size_t base = (size_t)n * E_ + e;
    union { uint4 q; unsigned short u[8]; } zin;
    zin.q = *(const uint4*)&z[base];
    float v[8];
    #pragma unroll
    for (int i = 0; i < 8; ++i) v[i] = bf2f(zin.u[i]);

    float sm = 0.f;
    #pragma unroll
    for (int i = 0; i < 8; ++i) sm += v[i];
    #pragma unroll
    for (int msk = 1; msk < 64; msk <<= 1) sm += __shfl_xor(sm, msk);
    float mu = sm * (1.f / 512.f);

    float ss = 0.f;
    #pragma unroll
    for (int i = 0; i < 8; ++i) { v[i] -= mu; ss += v[i] * v[i]; }
    #pragma unroll
    for (int msk = 1; msk < 64; msk <<= 1) ss += __shfl_xor(ss, msk);
    float rstd = rsqrtf(ss * (1.f / 512.f) + 1e-5f);

    float4 sc0 = *(const float4*)&s[e],    sc1 = *(const float4*)&s[e + 4];
    float4 bp0 = *(const float4*)&bpar[e], bp1 = *(const float4*)&bpar[e + 4];
    float o[8];
    o[0] = v[0] * rstd * sc0.x + bp0.x; o[1] = v[1] * rstd * sc0.y + bp0.y;
    o[2] = v[2] * rstd * sc0.z + bp0.z; o[3] = v[3] * rstd * sc0.w + bp0.w;
    o[4] = v[4] * rstd * sc1.x + bp1.x; o[5] = v[5] * rstd * sc1.y + bp1.y;
    o[6] = v[6] * rstd * sc1.z + bp1.z; o[7] = v[7] * rstd * sc1.w + bp1.w;
    union { unsigned short u[8]; uint4 q; } pk;
    #pragma unroll
    for (int i = 0; i < 8; ++i) pk.u[i] = f2bf(o[i]);
    *(uint4*)&outB[base] = pk.q;
}

// ---------------- head GEMM + fused per-row loss, BM=32, M x K split ---------
__global__ __launch_bounds__(256) void head_loss_kernel(
    const unsigned short* __restrict__ A, const unsigned short* __restrict__ W,
    const float* __restrict__ bias, const int* __restrict__ tgt,
    float* __restrict__ out_logits, float* __restrict__ rowloss)
{
    __shared__ unsigned short Asm[2][32 * 64];    // 2 x 4 KB
    __shared__ unsigned short Bsm[2][128 * 64];   // 2 x 16 KB
    int tid = threadIdx.x;
    int wv = tid >> 6, ln = tid & 63;
    int lquad = ln >> 4, lmod = ln & 15;
    int mh = wv & 1, kh = wv >> 1;
    int m0 = blockIdx.x * 32;

    floatx4 acc[8] = {};

    auto stage = [&](int k0, int pb) {
        {
            int cc = tid;
            int r = cc >> 3, k8s = (cc & 7) ^ (r & 7);
            gload_lds16(A + (size_t)(m0 + r) * E_ + k0 + 8 * k8s,
                        &Asm[pb][512 * wv]);
        }
        #pragma unroll
        for (int c = 0; c < 4; ++c) {
            int cc = tid + 256 * c;
            int r = cc >> 3, k8s = (cc & 7) ^ (r & 7);
            gload_lds16(W + (size_t)r * E_ + k0 + 8 * k8s,
                        &Bsm[pb][2048 * c + 512 * wv]);
        }
    };

    stage(0, 0);
    __syncthreads();
    for (int t = 0; t < 8; ++t) {
        int pb = t & 1;
        if (t < 7) stage((t + 1) << 6, pb ^ 1);
        bf16x8 af = *(const bf16x8*)&Asm[pb][SW(16 * mh + lmod, 4 * kh + lquad)];
        #pragma unroll
        for (int j = 0; j < 8; ++j) {
            bf16x8 bf = *(const bf16x8*)&Bsm[pb][SW(16 * j + lmod, 4 * kh + lquad)];
            acc[j] = __builtin_amdgcn_mfma_f32_16x16x32_bf16(af, bf, acc[j], 0, 0, 0);
        }
        if (t < 7) __syncthreads();
    }

    __syncthreads();
    float* redF = (float*)&Bsm[0][0];
    if (kh == 1) {
        #pragma unroll
        for (int j = 0; j < 8; ++j)
            *(floatx4*)&redF[mh * 2048 + ln * 32 + (((j ^ (ln & 7))) << 2)] = acc[j];
    }
    __syncthreads();
    if (kh == 0) {
        float bj[8];
        #pragma unroll
        for (int j = 0; j < 8; ++j) bj[j] = bias[16 * j + lmod];
        floatx4 part[8];
        #pragma unroll
        for (int j = 0; j < 8; ++j)
            part[j] = *(const floatx4*)&redF[mh * 2048 + ln * 32 + (((j ^ (ln & 7))) << 2)];
        #pragma unroll
        for (int v = 0; v < 4; ++v) {
            int m = m0 + 16 * mh + 4 * lquad + v;
            float x[8];
            float mx = -1e30f, sx = 0.f;
            #pragma unroll
            for (int j = 0; j < 8; ++j) {
                x[j] = acc[j][v] + part[j][v] + bj[j];
                out_logits[(size_t)m * V_ + 16 * j + lmod] = x[j];
                mx = fmaxf(mx, x[j]); sx += x[j];
            }
            #pragma unroll
            for (int msk = 1; msk < 16; msk <<= 1) mx = fmaxf(mx, __shfl_xor(mx, msk));
            float se = 0.f;
            #pragma unroll
            for (int j = 0; j < 8; ++j) se += __expf(x[j] - mx);
            #pragma unroll
            for (int msk = 1; msk < 16; msk <<= 1) {
                se += __shfl_xor(se, msk);
                sx += __shfl_xor(sx, msk);
            }
            int t = tgt[m];
            float cand = 0.f;
            #pragma unroll
            for (int j = 0; j < 8; ++j) cand = ((t >> 4) == j) ? x[j] : cand;
            float xt = __shfl(cand, (ln & 48) | (t & 15));
            if (lmod == 0) {
                float lse = mx + __logf(se);
                rowloss[m] = 0.9f * (lse - xt) + 0.1f * (lse - sx * (1.f / 128.f));
            }
        }
    }
}

__global__ __launch_bounds__(256) void loss_reduce_kernel(
    const float* __restrict__ rowloss, float* __restrict__ out)
{
    int tid = threadIdx.x;
    float sm = 0.f;
    for (int idx = tid; idx < N_; idx += 256) sm += rowloss[idx];
    #pragma unroll
    for (int off = 32; off; off >>= 1) sm += __shfl_down(sm, off, 64);
    __shared__ float red[4];
    int lane = tid & 63, w = tid >> 6;
    if (lane == 0) red[w] = sm;
    __syncthreads();
    if (tid == 0) out[0] = (red[0] + red[1] + red[2] + red[3]) * (1.f / (float)N_);
}

extern "C" void kernel_launch(void* const* d_in, const int* in_sizes, int n_in,
                              void* d_out, int out_size, void* d_ws, size_t ws_size,
                              hipStream_t stream)
{
    (void)in_sizes; (void)n_in; (void)out_size; (void)ws_size;
    const int* toks     = (const int*)d_in[0];
    const int* tgts     = (const int*)d_in[1];
    const float* emb    = (const float*)d_in[2];
    const float* qkv_w  = (const float*)d_in[3];
    const float* qkv_b  = (const float*)d_in[4];
    const float* aff1_w = (const float*)d_in[5];
    const float* aff1_b = (const float*)d_in[6];
    const float* aff2_w = (const float*)d_in[7];
    const float* aff2_b = (const float*)d_in[8];
    const float* ffn1_w = (const float*)d_in[9];
    const float* ffn1_b = (const float*)d_in[10];
    const float* ffn2_w = (const float*)d_in[11];
    const float* ffn2_b = (const float*)d_in[12];
    const float* ln1_s  = (const float*)d_in[13];
    const float* ln1_b  = (const float*)d_in[14];
    const float* ln2_s  = (const float*)d_in[15];
    const float* ln2_b  = (const float*)d_in[16];
    const float* head_w = (const float*)d_in[17];
    const float* head_b = (const float*)d_in[18];

    char* p = (char*)d_ws;
    auto carve = [&](size_t bytes) { char* r = p; p += (bytes + 255) & ~(size_t)255; return (void*)r; };
    unsigned short* wb_all  = (unsigned short*)carve((size_t)CVT_TOT * 2);
    unsigned short* wb_qkv  = wb_all;
    unsigned short* wb_aff1 = wb_qkv  + (size_t)CVT_N0;
    unsigned short* wb_aff2 = wb_aff1 + (size_t)CVT_N1;
    unsigned short* wb_ffn1 = wb_aff2 + (size_t)CVT_N1;
    unsigned short* wb_ffn2 = wb_ffn1 + (size_t)CVT_N1;
    unsigned short* wb_head = wb_ffn2 + (size_t)CVT_N1;
    unsigned short* x_b     = (unsigned short*)carve((size_t)N_ * E_ * 2);
    unsigned short* qkv_bf  = (unsigned short*)carve((size_t)N_ * E3_ * 2);
    unsigned short* att_b   = (unsigned short*)carve((size_t)N_ * E_ * 2);
    unsigned short* h_b     = (unsigned short*)carve((size_t)N_ * E_ * 2);
    unsigned short* z_b     = (unsigned short*)carve((size_t)N_ * E_ * 2);
    unsigned short* o1_b    = (unsigned short*)carve((size_t)N_ * E_ * 2);
    float*          rowl    = (float*)carve((size_t)N_ * 4);
    float*          vtile   = (float*)carve((size_t)32 * 16 * 64 * 4);
    unsigned short* vt_g    = (unsigned short*)carve((size_t)32 * 64 * T_ * 2);  // 4 MB

    float* out_logits = (float*)d_out;
    float* out_loss   = out_logits + (size_t)N_ * V_;

    cvt_all_kernel<<<dim3(CVT_TOT / 2048), 256, 0, stream>>>(
        qkv_w, aff1_w, aff2_w, ffn1_w, ffn2_w, head_w, wb_all);

    embed_kernel<<<dim3((N_ * E_) / 256), 256, 0, stream>>>(toks, emb, x_b);

    for (int l = 0; l < L_; ++l) {
        gemm_qkv<<<dim3(E3_/64, N_/256), 256, 0, stream>>>(
            x_b, wb_qkv + (size_t)l * E3_ * E_, qkv_b + (size_t)l * E3_,
            qkv_bf, vt_g, vtile, E_);
        attn_mfma<<<dim3(32, 16), 256, 0, stream>>>(qkv_bf, vt_g, vtile, att_b);
        gemm64<1,0><<<dim3(E_/64, N_/64), 256, 0, stream>>>(
            att_b, wb_aff1 + (size_t)l * E_ * E_, aff1_b + (size_t)l * E_,
            nullptr, h_b, N_, E_, E_);
        gemm64<0,1><<<dim3(E_/64, N_/64), 256, 0, stream>>>(
            h_b, wb_aff2 + (size_t)l * E_ * E_, aff2_b + (size_t)l * E_,
            x_b, z_b, N_, E_, E_);                  // z_b = mlp_out + x (bf16)
        ln_kernel<<<dim3(N_/4), 256, 0, stream>>>(
            z_b, ln1_s + (size_t)l * E_, ln1_b + (size_t)l * E_, o1_b);
        gemm64<1,0><<<dim3(E_/64, N_/64), 256, 0, stream>>>(
            o1_b, wb_ffn1 + (size_t)l * E_ * E_, ffn1_b + (size_t)l * E_,
            nullptr, h_b, N_, E_, E_);
        gemm64<0,1><<<dim3(E_/64, N_/64), 256, 0, stream>>>(
            h_b, wb_ffn2 + (size_t)l * E_ * E_, ffn2_b + (size_t)l * E_,
            o1_b, z_b, N_, E_, E_);                 // z_b = ffn_out + o1 (bf16)
        ln_kernel<<<dim3(N_/4), 256, 0, stream>>>(
            z_b, ln2_s + (size_t)l * E_, ln2_b + (size_t)l * E_, x_b);
    }

    head_loss_kernel<<<dim3(N_/32), 256, 0, stream>>>(
        x_b, wb_head, head_b, tgts, out_logits, rowl);
    loss_reduce_kernel<<<dim3(1), 256, 0, stream>>>(rowl, out_loss);
}

// Round 14
// 688.191 us; speedup vs baseline: 1.0367x; 1.0367x over previous
//
#include <hip/hip_runtime.h>

// 8-layer transformer LM forward. V=128, E=512, L=8, H=8, B=4, T=1024.
// Round 21: revert QKV to BM=128 (768 blocks = exactly 3 blocks/CU). R20's
// BM=256 gave 384 blocks = 1.5 waves of blocks -> half-empty second round
// (grid-quantization loss > per-block read savings). KEPT from R20: bf16
// pre-LN stream z_b (aff2/ffn2 write bf16, ln reads bf16) + bf16 residual.
// Base otherwise = R19/R20 hybrid: KVBLK=128 mask-specialized attn, M x K
// split gemm64, BM=32 fused head+loss.

#define V_  128
#define E_  512
#define L_  8
#define H_  8
#define B_  4
#define T_  1024
#define N_  (B_*T_)    // 4096 tokens
#define DH_ 64
#define E3_ 1536

typedef __attribute__((ext_vector_type(8))) short   bf16x8;   // MFMA A/B frag
typedef __attribute__((ext_vector_type(4))) float   floatx4;  // MFMA C/D frag

// swizzled LDS offset (ushort units): 64-wide rows, 8-elem chunks XORed by row&7
#define SW(row,k8) (((row) << 6) + ((((k8) ^ ((row) & 7))) << 3))
// 128-wide rows (16 chunks), chunk XORed by row&7 within low 3 bits
#define SW128(row,c) (((row) << 7) + ((((c) ^ ((row) & 7))) << 3))

__device__ __forceinline__ unsigned short f2bf(float f) {
    union { float f; unsigned int i; } v; v.f = f;
    unsigned int x = v.i;
    return (unsigned short)((x + 0x7fffu + ((x >> 16) & 1u)) >> 16);  // RNE
}
__device__ __forceinline__ float bf2f(unsigned short u) {
    union { unsigned int i; float f; } v; v.i = ((unsigned int)u) << 16; return v.f;
}
__device__ __forceinline__ void gload_lds16(const void* g, void* l) {
    __builtin_amdgcn_global_load_lds(
        (const __attribute__((address_space(1))) unsigned int*)g,
        (__attribute__((address_space(3))) unsigned int*)l, 16, 0, 0);
}

// XCD-grouped remap: grid (nx, ny), ny%8==0.
__device__ __forceinline__ void xcd_remap(int& mstrip, int& nblk) {
    int nx = gridDim.x;
    int flat = blockIdx.y * nx + blockIdx.x;
    int xcd = flat & 7;
    int j = flat >> 3;
    int per_xcd = gridDim.y >> 3;
    mstrip = xcd * per_xcd + j / nx;
    nblk = j % nx;
}

// ---------------- single-dispatch fp32 -> bf16 weight convert (8-wide) -------
#define CVT_N0 6291456
#define CVT_N1 2097152
#define CVT_TOT (CVT_N0 + 4*CVT_N1 + V_*E_)
__global__ void cvt_all_kernel(const float* __restrict__ s0, const float* __restrict__ s1,
                               const float* __restrict__ s2, const float* __restrict__ s3,
                               const float* __restrict__ s4, const float* __restrict__ s5,
                               unsigned short* __restrict__ dst) {
    long i = (long)(blockIdx.x * blockDim.x + threadIdx.x) * 8;
    if (i >= CVT_TOT) return;
    const float* src; long off;
    if      (i < CVT_N0)               { src = s0; off = i; }
    else if (i < CVT_N0 + CVT_N1)      { src = s1; off = i - CVT_N0; }
    else if (i < CVT_N0 + 2*CVT_N1)    { src = s2; off = i - CVT_N0 - CVT_N1; }
    else if (i < CVT_N0 + 3*CVT_N1)    { src = s3; off = i - CVT_N0 - 2L*CVT_N1; }
    else if (i < CVT_N0 + 4*CVT_N1)    { src = s4; off = i - CVT_N0 - 3L*CVT_N1; }
    else                               { src = s5; off = i - CVT_N0 - 4L*CVT_N1; }
    float4 v0 = *(const float4*)(src + off);
    float4 v1 = *(const float4*)(src + off + 4);
    ushort4 o0, o1;
    o0.x = f2bf(v0.x); o0.y = f2bf(v0.y); o0.z = f2bf(v0.z); o0.w = f2bf(v0.w);
    o1.x = f2bf(v1.x); o1.y = f2bf(v1.y); o1.z = f2bf(v1.z); o1.w = f2bf(v1.w);
    *(ushort4*)(dst + i)     = o0;
    *(ushort4*)(dst + i + 4) = o1;
}

// ---------------- embedding: write bf16 only ----------------
__global__ void embed_kernel(const int* __restrict__ tok, const float* __restrict__ emb,
                             unsigned short* __restrict__ xb) {
    int idx = blockIdx.x * blockDim.x + threadIdx.x;
    if (idx >= N_ * E_) return;
    int n = idx >> 9;
    int e = idx & (E_ - 1);
    xb[idx] = f2bf(emb[tok[n] * E_ + e]);
}

// ---------------- MFMA GEMM: BM=64, BN=64, paired-K, M x K wave split --------
template<int RELU, int ADDRES>
__global__ __launch_bounds__(256) void gemm64(
    const unsigned short* __restrict__ A, const unsigned short* __restrict__ W,
    const float* __restrict__ bias, const unsigned short* __restrict__ resB,
    unsigned short* __restrict__ Cb,
    int M, int Nout, int K)
{
    __shared__ unsigned short Asm[4][64 * 64];
    __shared__ unsigned short Bsm[4][64 * 64];
    int tid = threadIdx.x;
    int wv = tid >> 6, ln = tid & 63;
    int lquad = ln >> 4, lmod = ln & 15;
    int mh = wv & 1, kh = wv >> 1;
    int mstrip, nblk;
    xcd_remap(mstrip, nblk);
    int m0 = mstrip * 64, n0 = nblk * 64;

    floatx4 acc[2][4] = {};

    auto stage = [&](int k0, int s) {
        #pragma unroll
        for (int c = 0; c < 2; ++c) {
            int cc = tid + 256 * c;
            int r = cc >> 3, k8s = (cc & 7) ^ (r & 7);
            gload_lds16(A + (size_t)(m0 + r) * K + k0 + 8 * k8s,
                        &Asm[s][2048 * c + 512 * wv]);
        }
        #pragma unroll
        for (int c = 0; c < 2; ++c) {
            int cc = tid + 256 * c;
            int r = cc >> 3, k8s = (cc & 7) ^ (r & 7);
            gload_lds16(W + (size_t)(n0 + r) * K + k0 + 8 * k8s,
                        &Bsm[s][2048 * c + 512 * wv]);
        }
    };

    int np = K >> 7;
    stage(0, 0);
    stage(64, 1);
    __syncthreads();

    for (int t = 0; t < np; ++t) {
        if (t + 1 < np) {
            stage((2 * t + 2) << 6, (2 * t + 2) & 3);
            stage((2 * t + 3) << 6, (2 * t + 3) & 3);
        }
        #pragma unroll
        for (int half = 0; half < 2; ++half) {
            int s = (2 * t + half) & 3;
            bf16x8 af[2], bfr[4];
            #pragma unroll
            for (int i = 0; i < 2; ++i)
                af[i] = *(const bf16x8*)&Asm[s][SW(32 * mh + 16 * i + lmod, 4 * kh + lquad)];
            #pragma unroll
            for (int j = 0; j < 4; ++j)
                bfr[j] = *(const bf16x8*)&Bsm[s][SW(16 * j + lmod, 4 * kh + lquad)];
            #pragma unroll
            for (int i = 0; i < 2; ++i)
                #pragma unroll
                for (int j = 0; j < 4; ++j)
                    acc[i][j] = __builtin_amdgcn_mfma_f32_16x16x32_bf16(af[i], bfr[j], acc[i][j], 0, 0, 0);
        }
        if (t + 1 < np) __syncthreads();
    }

    float* redF = (float*)&Asm[0][0];
    if (kh == 1) {
        #pragma unroll
        for (int i = 0; i < 2; ++i)
            #pragma unroll
            for (int j = 0; j < 4; ++j) {
                int bidx = i * 4 + j;
                *(floatx4*)&redF[mh * 2048 + ln * 32 + (((bidx ^ (ln & 7))) << 2)] = acc[i][j];
            }
    }
    __syncthreads();
    if (kh == 0) {
        #pragma unroll
        for (int i = 0; i < 2; ++i)
            #pragma unroll
            for (int j = 0; j < 4; ++j) {
                int bidx = i * 4 + j;
                floatx4 part = *(const floatx4*)&redF[mh * 2048 + ln * 32 + (((bidx ^ (ln & 7))) << 2)];
                int n = n0 + 16 * j + lmod;
                float bj = bias[n];
                #pragma unroll
                for (int v = 0; v < 4; ++v) {
                    int m = m0 + 32 * mh + 16 * i + 4 * lquad + v;
                    float val = acc[i][j][v] + part[v] + bj;
                    if (ADDRES) val += bf2f(resB[(size_t)m * Nout + n]);
                    if (RELU) val = fmaxf(val, 0.f);
                    Cb[(size_t)m * Nout + n] = f2bf(val);
                }
            }
    }
}

// ---------------- QKV GEMM, BM=128 (768 blocks = 3/CU), fused V-transpose ----
__global__ __launch_bounds__(256) void gemm_qkv(
    const unsigned short* __restrict__ A, const unsigned short* __restrict__ W,
    const float* __restrict__ bias, unsigned short* __restrict__ Cb,
    unsigned short* __restrict__ vt_g, float* __restrict__ vtile, int K)
{
    __shared__ unsigned short Asm[2][128 * 64];
    __shared__ unsigned short Bsm[2][64 * 64];
    __shared__ float vred[4][64];
    int tid = threadIdx.x;
    int wv = tid >> 6, ln = tid & 63;
    int lquad = ln >> 4, lmod = ln & 15;
    int mstrip, nblk;
    xcd_remap(mstrip, nblk);
    int m0 = mstrip * 128, n0 = nblk * 64;

    floatx4 acc[2][4] = {};

    auto stage = [&](int k0, int pb) {
        #pragma unroll
        for (int c = 0; c < 4; ++c) {
            int cc = tid + 256 * c;
            int r = cc >> 3, k8s = (cc & 7) ^ (r & 7);
            gload_lds16(A + (size_t)(m0 + r) * K + k0 + 8 * k8s,
                        &Asm[pb][2048 * c + 512 * wv]);
        }
        #pragma unroll
        for (int c = 0; c < 2; ++c) {
            int cc = tid + 256 * c;
            int r = cc >> 3, k8s = (cc & 7) ^ (r & 7);
            gload_lds16(W + (size_t)(n0 + r) * K + k0 + 8 * k8s,
                        &Bsm[pb][2048 * c + 512 * wv]);
        }
    };

    int nt = K >> 6;
    stage(0, 0);
    __syncthreads();
    for (int t = 0; t < nt; ++t) {
        int pb = t & 1;
        if (t + 1 < nt) stage((t + 1) << 6, pb ^ 1);
        #pragma unroll
        for (int ks = 0; ks < 2; ++ks) {
            bf16x8 af[2], bfr[4];
            #pragma unroll
            for (int i = 0; i < 2; ++i)
                af[i] = *(const bf16x8*)&Asm[pb][SW(32 * wv + 16 * i + lmod, ks * 4 + lquad)];
            #pragma unroll
            for (int j = 0; j < 4; ++j)
                bfr[j] = *(const bf16x8*)&Bsm[pb][SW(16 * j + lmod, ks * 4 + lquad)];
            #pragma unroll
            for (int i = 0; i < 2; ++i)
                #pragma unroll
                for (int j = 0; j < 4; ++j)
                    acc[i][j] = __builtin_amdgcn_mfma_f32_16x16x32_bf16(af[i], bfr[j], acc[i][j], 0, 0, 0);
        }
        if (t + 1 < nt) __syncthreads();
    }

    if ((n0 % 192) != 128) {
        #pragma unroll
        for (int i = 0; i < 2; ++i)
            #pragma unroll
            for (int j = 0; j < 4; ++j) {
                int n = n0 + 16 * j + lmod;
                float bj = bias[n];
                #pragma unroll
                for (int v = 0; v < 4; ++v) {
                    int m = m0 + 32 * wv + 16 * i + 4 * lquad + v;
                    Cb[(size_t)m * E3_ + n] = f2bf(acc[i][j][v] + bj);
                }
            }
    } else {
        int h = n0 / 192;
        int b = m0 >> 10;
        int bh = b * 8 + h;
        int t0 = m0 & 1023;
        int kt0 = t0 >> 6;
        float sj[4] = {0.f, 0.f, 0.f, 0.f};
        #pragma unroll
        for (int j = 0; j < 4; ++j) {
            float bj = bias[n0 + 16 * j + lmod];
            #pragma unroll
            for (int i = 0; i < 2; ++i) {
                union { unsigned short u[4]; uint2 q; } pk;
                #pragma unroll
                for (int v = 0; v < 4; ++v) {
                    unsigned short r = f2bf(acc[i][j][v] + bj);
                    pk.u[v] = r;
                    sj[j] += bf2f(r);
                }
                int t = t0 + 32 * wv + 16 * i + 4 * lquad;
                *(uint2*)&vt_g[((size_t)(bh * 64 + 16 * j + lmod)) * T_ + t] = pk.q;
            }
        }
        #pragma unroll
        for (int j = 0; j < 4; ++j) {
            sj[j] += __shfl_xor(sj[j], 16);
            sj[j] += __shfl_xor(sj[j], 32);
        }
        if (lquad == 0) {
            #pragma unroll
            for (int j = 0; j < 4; ++j) vred[wv][16 * j + lmod] = sj[j];
        }
        __syncthreads();
        if (tid < 128) {
            int half = tid >> 6, d = tid & 63;
            vtile[((size_t)bh * 16 + kt0 + half) * 64 + d] =
                vred[2 * half][d] + vred[2 * half + 1][d];
        }
    }
}

// ---------------- MFMA flash attention, KVBLK=128, mask-specialized ----------
__global__ __launch_bounds__(256) void attn_mfma(const unsigned short* __restrict__ qkv,
                                                 const unsigned short* __restrict__ vt_g,
                                                 const float* __restrict__ vtile,
                                                 unsigned short* __restrict__ outb)
{
    __shared__ unsigned short Qs[64 * 64];         // [q][d]   8 KB
    __shared__ unsigned short Ks[2][128 * 64];     // [k][d]  32 KB, dbuf
    __shared__ unsigned short Vs[64 * 128];        // [d][k]  16 KB, single
    __shared__ unsigned short Ps[64 * 128];        // [q][k]  16 KB, wave-private rows

    int tid = threadIdx.x;
    int wv = tid >> 6, ln = tid & 63;
    int lquad = ln >> 4, lmod = ln & 15;
    int bh = blockIdx.x;
    int y = blockIdx.y;
    int qt = (y < 8) ? y : 23 - y;                 // complementary pairing
    int b = bh >> 3, h = bh & 7;
    int q0 = qt * 64;
    int nt = (qt >> 1) + 1;                        // 128-wide k-tiles
    const float scale = 0.125f;
    size_t base = (size_t)b * T_ * E3_ + h * 192;

    auto stageK = [&](int k0, int pb) {
        #pragma unroll
        for (int c = 0; c < 4; ++c) {
            int cc = tid + 256 * c;
            int r = cc >> 3, k8s = (cc & 7) ^ (r & 7);
            gload_lds16(qkv + base + (size_t)(k0 + r) * E3_ + 64 + 8 * k8s,
                        &Ks[pb][2048 * c + 512 * wv]);
        }
    };
    auto stageV = [&](int k0) {
        #pragma unroll
        for (int c = 0; c < 4; ++c) {
            int cc = tid + 256 * c;
            int r = cc >> 4, c16 = cc & 15;
            int k8s = c16 ^ (r & 7);
            gload_lds16(vt_g + ((size_t)(bh * 64 + r)) * T_ + k0 + 8 * k8s,
                        &Vs[2048 * c + 512 * wv]);
        }
    };

    // prologue: Q + K tile 0
    #pragma unroll
    for (int c = 0; c < 2; ++c) {
        int cc = tid + 256 * c;
        int r = cc >> 3, k8s = (cc & 7) ^ (r & 7);
        gload_lds16(qkv + base + (size_t)(q0 + r) * E3_ + 8 * k8s, Qs + 2048 * c + 512 * wv);
    }
    stageK(0, 0);
    __syncthreads();

    // hoisted Q fragments (loop-invariant)
    bf16x8 aq[2];
    #pragma unroll
    for (int ks = 0; ks < 2; ++ks)
        aq[ks] = *(const bf16x8*)&Qs[SW(16 * wv + lmod, ks * 4 + lquad)];

    float lrow[4] = {0.f, 0.f, 0.f, 0.f};
    floatx4 Oa[4] = {};

    for (int t = 0; t < nt; ++t) {
        int pb = t & 1;
        int k0 = t * 128;
        stageV(k0);                                 // lands under QK + softmax
        if (t + 1 < nt) stageK(k0 + 128, pb ^ 1);   // prefetch next K

        // S strip = Q[16 rows] . K^T (128 cols)
        floatx4 sacc[8] = {};
        #pragma unroll
        for (int ks = 0; ks < 2; ++ks)
            #pragma unroll
            for (int j = 0; j < 8; ++j) {
                bf16x8 bk = *(const bf16x8*)&Ks[pb][SW(16 * j + lmod, ks * 4 + lquad)];
                sacc[j] = __builtin_amdgcn_mfma_f32_16x16x32_bf16(aq[ks], bk, sacc[j], 0, 0, 0);
            }

        // softmax: p = exp(s*scale); only the last tile has masked elements.
        if (t + 1 < nt) {
            #pragma unroll
            for (int v = 0; v < 4; ++v) {
                int row = 16 * wv + 4 * lquad + v;
                #pragma unroll
                for (int j = 0; j < 8; ++j) {
                    float p = __expf(sacc[j][v] * scale);
                    lrow[v] += p;
                    int col = 16 * j + lmod;
                    Ps[SW128(row, col >> 3) + (col & 7)] = f2bf(p);
                }
            }
        } else {
            #pragma unroll
            for (int v = 0; v < 4; ++v) {
                int qg = q0 + 16 * wv + 4 * lquad + v;
                int row = 16 * wv + 4 * lquad + v;
                #pragma unroll
                for (int j = 0; j < 8; ++j) {
                    int kg = k0 + 16 * j + lmod;
                    float p = (kg <= qg) ? __expf(sacc[j][v] * scale) : 1.0f;
                    lrow[v] += p;
                    int col = 16 * j + lmod;
                    Ps[SW128(row, col >> 3) + (col & 7)] = f2bf(p);
                }
            }
        }

        // V ready for ALL waves + own Ps drained; K prefetch stays in flight
        if (t + 1 < nt) asm volatile("s_waitcnt vmcnt(4) lgkmcnt(0)" ::: "memory");
        else            asm volatile("s_waitcnt vmcnt(0) lgkmcnt(0)" ::: "memory");
        __builtin_amdgcn_s_barrier();
        __builtin_amdgcn_sched_barrier(0);

        // O += P . V  (K=128 -> 4 ks-steps)
        #pragma unroll
        for (int ks2 = 0; ks2 < 4; ++ks2) {
            bf16x8 ap = *(const bf16x8*)&Ps[SW128(16 * wv + lmod, 4 * ks2 + lquad)];
            #pragma unroll
            for (int f = 0; f < 4; ++f) {
                bf16x8 bv = *(const bf16x8*)&Vs[SW128(16 * f + lmod, 4 * ks2 + lquad)];
                Oa[f] = __builtin_amdgcn_mfma_f32_16x16x32_bf16(ap, bv, Oa[f], 0, 0, 0);
            }
        }
        if (t + 1 < nt) __syncthreads();   // K landed + WAR on Vs/Ps/Ks
    }

    #pragma unroll
    for (int v = 0; v < 4; ++v)
        #pragma unroll
        for (int msk = 1; msk < 16; msk <<= 1) lrow[v] += __shfl_xor(lrow[v], msk);

    int s0 = 2 * nt;
    if (s0 < 16) {
        float Km = (float)((16 - s0) * 64);
        #pragma unroll
        for (int v = 0; v < 4; ++v) lrow[v] += Km;
        #pragma unroll
        for (int f = 0; f < 4; ++f) {
            float sv = 0.f;
            for (int kt = s0; kt < 16; ++kt)
                sv += vtile[((size_t)bh * 16 + kt) * 64 + 16 * f + lmod];
            #pragma unroll
            for (int v = 0; v < 4; ++v) Oa[f][v] += sv;
        }
    }

    #pragma unroll
    for (int f = 0; f < 4; ++f)
        #pragma unroll
        for (int v = 0; v < 4; ++v) {
            int q = q0 + 16 * wv + 4 * lquad + v;
            outb[(size_t)(b * T_ + q) * E_ + h * DH_ + 16 * f + lmod] = f2bf(Oa[f][v] / lrow[v]);
        }
}

// ---------------- LN: bf16 in (pre-LN z), bf16 out ---------------------------
__global__ __launch_bounds__(256) void ln_kernel(
    const unsigned short* __restrict__ z,
    const float* __restrict__ s, const float* __restrict__ bpar,
    unsigned short* __restrict__ outB)
{
    int tid = threadIdx.x, wv = tid >> 6, ln = tid & 63;
    int n = blockIdx.x * 4 + wv;
    int e = ln * 8;
    size_t base = (size_t)n * E_ + e;
    union { uint4 q; unsigned short u[8]; } zin;
    zin.q = *(const uint4*)&z[base];
    float v[8];
    #pragma unroll
    for (int i = 0; i < 8; ++i) v[i] = bf2f(zin.u[i]);

    float sm = 0.f;
    #pragma unroll
    for (int i = 0; i < 8; ++i) sm += v[i];
    #pragma unroll
    for (int msk = 1; msk < 64; msk <<= 1) sm += __shfl_xor(sm, msk);
    float mu = sm * (1.f / 512.f);

    float ss = 0.f;
    #pragma unroll
    for (int i = 0; i < 8; ++i) { v[i] -= mu; ss += v[i] * v[i]; }
    #pragma unroll
    for (int msk = 1; msk < 64; msk <<= 1) ss += __shfl_xor(ss, msk);
    float rstd = rsqrtf(ss * (1.f / 512.f) + 1e-5f);

    float4 sc0 = *(const float4*)&s[e],    sc1 = *(const float4*)&s[e + 4];
    float4 bp0 = *(const float4*)&bpar[e], bp1 = *(const float4*)&bpar[e + 4];
    float o[8];
    o[0] = v[0] * rstd * sc0.x + bp0.x; o[1] = v[1] * rstd * sc0.y + bp0.y;
    o[2] = v[2] * rstd * sc0.z + bp0.z; o[3] = v[3] * rstd * sc0.w + bp0.w;
    o[4] = v[4] * rstd * sc1.x + bp1.x; o[5] = v[5] * rstd * sc1.y + bp1.y;
    o[6] = v[6] * rstd * sc1.z + bp1.z; o[7] = v[7] * rstd * sc1.w + bp1.w;
    union { unsigned short u[8]; uint4 q; } pk;
    #pragma unroll
    for (int i = 0; i < 8; ++i) pk.u[i] = f2bf(o[i]);
    *(uint4*)&outB[base] = pk.q;
}

// ---------------- head GEMM + fused per-row loss, BM=32, M x K split ---------
__global__ __launch_bounds__(256) void head_loss_kernel(
    const unsigned short* __restrict__ A, const unsigned short* __restrict__ W,
    const float* __restrict__ bias, const int* __restrict__ tgt,
    float* __restrict__ out_logits, float* __restrict__ rowloss)
{
    __shared__ unsigned short Asm[2][32 * 64];    // 2 x 4 KB
    __shared__ unsigned short Bsm[2][128 * 64];   // 2 x 16 KB
    int tid = threadIdx.x;
    int wv = tid >> 6, ln = tid & 63;
    int lquad = ln >> 4, lmod = ln & 15;
    int mh = wv & 1, kh = wv >> 1;
    int m0 = blockIdx.x * 32;

    floatx4 acc[8] = {};

    auto stage = [&](int k0, int pb) {
        {
            int cc = tid;
            int r = cc >> 3, k8s = (cc & 7) ^ (r & 7);
            gload_lds16(A + (size_t)(m0 + r) * E_ + k0 + 8 * k8s,
                        &Asm[pb][512 * wv]);
        }
        #pragma unroll
        for (int c = 0; c < 4; ++c) {
            int cc = tid + 256 * c;
            int r = cc >> 3, k8s = (cc & 7) ^ (r & 7);
            gload_lds16(W + (size_t)r * E_ + k0 + 8 * k8s,
                        &Bsm[pb][2048 * c + 512 * wv]);
        }
    };

    stage(0, 0);
    __syncthreads();
    for (int t = 0; t < 8; ++t) {
        int pb = t & 1;
        if (t < 7) stage((t + 1) << 6, pb ^ 1);
        bf16x8 af = *(const bf16x8*)&Asm[pb][SW(16 * mh + lmod, 4 * kh + lquad)];
        #pragma unroll
        for (int j = 0; j < 8; ++j) {
            bf16x8 bf = *(const bf16x8*)&Bsm[pb][SW(16 * j + lmod, 4 * kh + lquad)];
            acc[j] = __builtin_amdgcn_mfma_f32_16x16x32_bf16(af, bf, acc[j], 0, 0, 0);
        }
        if (t < 7) __syncthreads();
    }

    __syncthreads();
    float* redF = (float*)&Bsm[0][0];
    if (kh == 1) {
        #pragma unroll
        for (int j = 0; j < 8; ++j)
            *(floatx4*)&redF[mh * 2048 + ln * 32 + (((j ^ (ln & 7))) << 2)] = acc[j];
    }
    __syncthreads();
    if (kh == 0) {
        float bj[8];
        #pragma unroll
        for (int j = 0; j < 8; ++j) bj[j] = bias[16 * j + lmod];
        floatx4 part[8];
        #pragma unroll
        for (int j = 0; j < 8; ++j)
            part[j] = *(const floatx4*)&redF[mh * 2048 + ln * 32 + (((j ^ (ln & 7))) << 2)];
        #pragma unroll
        for (int v = 0; v < 4; ++v) {
            int m = m0 + 16 * mh + 4 * lquad + v;
            float x[8];
            float mx = -1e30f, sx = 0.f;
            #pragma unroll
            for (int j = 0; j < 8; ++j) {
                x[j] = acc[j][v] + part[j][v] + bj[j];
                out_logits[(size_t)m * V_ + 16 * j + lmod] = x[j];
                mx = fmaxf(mx, x[j]); sx += x[j];
            }
            #pragma unroll
            for (int msk = 1; msk < 16; msk <<= 1) mx = fmaxf(mx, __shfl_xor(mx, msk));
            float se = 0.f;
            #pragma unroll
            for (int j = 0; j < 8; ++j) se += __expf(x[j] - mx);
            #pragma unroll
            for (int msk = 1; msk < 16; msk <<= 1) {
                se += __shfl_xor(se, msk);
                sx += __shfl_xor(sx, msk);
            }
            int t = tgt[m];
            float cand = 0.f;
            #pragma unroll
            for (int j = 0; j < 8; ++j) cand = ((t >> 4) == j) ? x[j] : cand;
            float xt = __shfl(cand, (ln & 48) | (t & 15));
            if (lmod == 0) {
                float lse = mx + __logf(se);
                rowloss[m] = 0.9f * (lse - xt) + 0.1f * (lse - sx * (1.f / 128.f));
            }
        }
    }
}

__global__ __launch_bounds__(256) void loss_reduce_kernel(
    const float* __restrict__ rowloss, float* __restrict__ out)
{
    int tid = threadIdx.x;
    float sm = 0.f;
    for (int idx = tid; idx < N_; idx += 256) sm += rowloss[idx];
    #pragma unroll
    for (int off = 32; off; off >>= 1) sm += __shfl_down(sm, off, 64);
    __shared__ float red[4];
    int lane = tid & 63, w = tid >> 6;
    if (lane == 0) red[w] = sm;
    __syncthreads();
    if (tid == 0) out[0] = (red[0] + red[1] + red[2] + red[3]) * (1.f / (float)N_);
}

extern "C" void kernel_launch(void* const* d_in, const int* in_sizes, int n_in,
                              void* d_out, int out_size, void* d_ws, size_t ws_size,
                              hipStream_t stream)
{
    (void)in_sizes; (void)n_in; (void)out_size; (void)ws_size;
    const int* toks     = (const int*)d_in[0];
    const int* tgts     = (const int*)d_in[1];
    const float* emb    = (const float*)d_in[2];
    const float* qkv_w  = (const float*)d_in[3];
    const float* qkv_b  = (const float*)d_in[4];
    const float* aff1_w = (const float*)d_in[5];
    const float* aff1_b = (const float*)d_in[6];
    const float* aff2_w = (const float*)d_in[7];
    const float* aff2_b = (const float*)d_in[8];
    const float* ffn1_w = (const float*)d_in[9];
    const float* ffn1_b = (const float*)d_in[10];
    const float* ffn2_w = (const float*)d_in[11];
    const float* ffn2_b = (const float*)d_in[12];
    const float* ln1_s  = (const float*)d_in[13];
    const float* ln1_b  = (const float*)d_in[14];
    const float* ln2_s  = (const float*)d_in[15];
    const float* ln2_b  = (const float*)d_in[16];
    const float* head_w = (const float*)d_in[17];
    const float* head_b = (const float*)d_in[18];

    char* p = (char*)d_ws;
    auto carve = [&](size_t bytes) { char* r = p; p += (bytes + 255) & ~(size_t)255; return (void*)r; };
    unsigned short* wb_all  = (unsigned short*)carve((size_t)CVT_TOT * 2);
    unsigned short* wb_qkv  = wb_all;
    unsigned short* wb_aff1 = wb_qkv  + (size_t)CVT_N0;
    unsigned short* wb_aff2 = wb_aff1 + (size_t)CVT_N1;
    unsigned short* wb_ffn1 = wb_aff2 + (size_t)CVT_N1;
    unsigned short* wb_ffn2 = wb_ffn1 + (size_t)CVT_N1;
    unsigned short* wb_head = wb_ffn2 + (size_t)CVT_N1;
    unsigned short* x_b     = (unsigned short*)carve((size_t)N_ * E_ * 2);
    unsigned short* qkv_bf  = (unsigned short*)carve((size_t)N_ * E3_ * 2);
    unsigned short* att_b   = (unsigned short*)carve((size_t)N_ * E_ * 2);
    unsigned short* h_b     = (unsigned short*)carve((size_t)N_ * E_ * 2);
    unsigned short* z_b     = (unsigned short*)carve((size_t)N_ * E_ * 2);
    unsigned short* o1_b    = (unsigned short*)carve((size_t)N_ * E_ * 2);
    float*          rowl    = (float*)carve((size_t)N_ * 4);
    float*          vtile   = (float*)carve((size_t)32 * 16 * 64 * 4);
    unsigned short* vt_g    = (unsigned short*)carve((size_t)32 * 64 * T_ * 2);  // 4 MB

    float* out_logits = (float*)d_out;
    float* out_loss   = out_logits + (size_t)N_ * V_;

    cvt_all_kernel<<<dim3(CVT_TOT / 2048), 256, 0, stream>>>(
        qkv_w, aff1_w, aff2_w, ffn1_w, ffn2_w, head_w, wb_all);

    embed_kernel<<<dim3((N_ * E_) / 256), 256, 0, stream>>>(toks, emb, x_b);

    for (int l = 0; l < L_; ++l) {
        gemm_qkv<<<dim3(E3_/64, N_/128), 256, 0, stream>>>(
            x_b, wb_qkv + (size_t)l * E3_ * E_, qkv_b + (size_t)l * E3_,
            qkv_bf, vt_g, vtile, E_);
        attn_mfma<<<dim3(32, 16), 256, 0, stream>>>(qkv_bf, vt_g, vtile, att_b);
        gemm64<1,0><<<dim3(E_/64, N_/64), 256, 0, stream>>>(
            att_b, wb_aff1 + (size_t)l * E_ * E_, aff1_b + (size_t)l * E_,
            nullptr, h_b, N_, E_, E_);
        gemm64<0,1><<<dim3(E_/64, N_/64), 256, 0, stream>>>(
            h_b, wb_aff2 + (size_t)l * E_ * E_, aff2_b + (size_t)l * E_,
            x_b, z_b, N_, E_, E_);                  // z_b = mlp_out + x (bf16)
        ln_kernel<<<dim3(N_/4), 256, 0, stream>>>(
            z_b, ln1_s + (size_t)l * E_, ln1_b + (size_t)l * E_, o1_b);
        gemm64<1,0><<<dim3(E_/64, N_/64), 256, 0, stream>>>(
            o1_b, wb_ffn1 + (size_t)l * E_ * E_, ffn1_b + (size_t)l * E_,
            nullptr, h_b, N_, E_, E_);
        gemm64<0,1><<<dim3(E_/64, N_/64), 256, 0, stream>>>(
            h_b, wb_ffn2 + (size_t)l * E_ * E_, ffn2_b + (size_t)l * E_,
            o1_b, z_b, N_, E_, E_);                 // z_b = ffn_out + o1 (bf16)
        ln_kernel<<<dim3(N_/4), 256, 0, stream>>>(
            z_b, ln2_s + (size_t)l * E_, ln2_b + (size_t)l * E_, x_b);
    }

    head_loss_kernel<<<dim3(N_/32), 256, 0, stream>>>(
        x_b, wb_head, head_b, tgts, out_logits, rowl);
    loss_reduce_kernel<<<dim3(1), 256, 0, stream>>>(rowl, out_loss);
}